// Round 1
// 98.053 us; speedup vs baseline: 1.0030x; 1.0030x over previous
//
#include <hip/hip_runtime.h>

#define TPB 256           // 4 waves: wave w = row w of 64 residues
#define RPB 64            // residues per block
#define ASTRIDE 21        // odd stride -> 2-way LDS alias (free)
#define FSTRIDE 148       // frame-row stride in floats: 148 % 32 = 4*odd ->
                          // r*FSTRIDE mod 32 cycles all 8 16B windows ->
                          // 8-way (= b128 minimum) instead of 32-way at 144

// ---------- helpers ----------

__device__ __forceinline__ void load16(float* M, const float* __restrict__ p) {
    const float4* q = reinterpret_cast<const float4*>(p);
    float4 v0 = q[0], v1 = q[1], v2 = q[2], v3 = q[3];
    M[0]=v0.x; M[1]=v0.y; M[2]=v0.z; M[3]=v0.w;
    M[4]=v1.x; M[5]=v1.y; M[6]=v1.z; M[7]=v1.w;
    M[8]=v2.x; M[9]=v2.y; M[10]=v2.z; M[11]=v2.w;
    M[12]=v3.x; M[13]=v3.y; M[14]=v3.z; M[15]=v3.w;
}

// w(1x4) = v(1x4) @ B(4x4 row-major)
__device__ __forceinline__ void vrow_mat(float* __restrict__ w,
                                         const float* __restrict__ v,
                                         const float* __restrict__ B) {
#pragma unroll
    for (int j = 0; j < 4; ++j) {
        float t = v[0] * B[0*4+j];
        t = fmaf(v[1], B[1*4+j], t);
        t = fmaf(v[2], B[2*4+j], t);
        t = fmaf(v[3], B[3*4+j], t);
        w[j] = t;
    }
}

// v = v @ rotX(c,s): cols 1,2 mix
__device__ __forceinline__ void vrotX(float* v, float c, float s) {
    float t1 = v[1], t2 = v[2];
    v[1] = fmaf(t2, s, t1*c);
    v[2] = fmaf(t2, c, -(t1*s));
}

// v = v @ rotZ(c,s): cols 0,1 mix
__device__ __forceinline__ void vrotZ(float* v, float c, float s) {
    float t0 = v[0], t1 = v[1];
    v[0] = fmaf(t1, s, t0*c);
    v[1] = fmaf(t1, c, -(t0*s));
}

__device__ __forceinline__ void rot_axis3(float* R, float ct, float st,
                                          float u0, float u1, float u2) {
    float omc = 1.0f - ct;
    R[0] = ct + u0*u0*omc;       R[1] = u0*u1*omc - u2*st;   R[2] = u0*u2*omc + u1*st;
    R[3] = u0*u1*omc + u2*st;    R[4] = ct + u1*u1*omc;      R[5] = u1*u2*omc - u0*st;
    R[6] = u0*u2*omc - u1*st;    R[7] = u1*u2*omc + u0*st;   R[8] = ct + u2*u2*omc;
}

__device__ __forceinline__ void st4(float* p, float a, float b, float c, float d) {
    *reinterpret_cast<float4*>(p) = make_float4(a, b, c, d);
}

// ---------- fused kernel ----------

extern "C" __global__ void __launch_bounds__(TPB, 4)
caac_kernel(const float* __restrict__ xyz,     // (L,3,3)
            const float* __restrict__ alphas,  // (L,10,2)
            const float* __restrict__ RTs,     // (22,7,4,4)
            const float* __restrict__ bxyz,    // (22,27,4)
            const int*   __restrict__ seq,     // (L)
            const int*   __restrict__ bidx,    // (22,27)
            float* __restrict__ outF,          // (L,9,4,4)
            float* __restrict__ outX,          // (L,27,3)
            int L)
{
    __shared__ float sF[RPB * FSTRIDE];   // 38.1 KB: frames, padded stride
    __shared__ int   sSeq[RPB];
    // staging aliases inside sF (consumed before sF is overwritten)
    float* sX = sF;            // RPB*9  floats
    float* sA = sF + RPB * 9;  // RPB*21 floats (padded)

    const int tid     = threadIdx.x;
    const int row     = tid >> 6;      // wave id = frame row (wave-uniform)
    const int r       = tid & 63;      // residue within block
    const int resBase = blockIdx.x * RPB;
    int nres = L - resBase; if (nres > RPB) nres = RPB;

    // ---- stage inputs coalesced ----
    for (int j = tid; j < nres * 9; j += TPB)
        sX[j] = xyz[(size_t)resBase * 9 + j];
    for (int j = tid; j < nres * 20; j += TPB) {
        int rr = j / 20, o = j - rr * 20;
        sA[rr * ASTRIDE + o] = alphas[(size_t)resBase * 20 + j];
    }
    for (int j = tid; j < nres; j += TPB)
        sSeq[j] = seq[resBase + j];
    __syncthreads();

    // ---- pull per-thread inputs to registers (before sF overwrite) ----
    float ca[10], sa[10];
    float v0[4] = {0.f, 0.f, 0.f, 1.f};     // my row of RTF0
    float v8[4] = {0.f, 0.f, 0.f, 1.f};     // my row of RTF8 (pre-chain)
    int s = 0;
    float M0t = 0.f;                        // translation component of my row

    const bool active = (r < nres);
    float e1x=0,e1y=0,e1z=0,e2x=0,e2y=0,e2z=0,e3x=0,e3y=0,e3z=0;

    if (active) {
        s = sSeq[r];
        const float* ap = sA + r * ASTRIDE;
#pragma unroll
        for (int k = 0; k < 10; ++k) {
            float a0 = ap[2*k], a1 = ap[2*k+1];
            float n = sqrtf(a0*a0 + a1*a1) + 1e-6f;
            ca[k] = a0 / n;
            sa[k] = a1 / n;
        }
        if (row < 3) {  // wave-uniform branch: waves 0..2 only
            const float* xp = sX + r * 9;
            float Nx=xp[0], Ny=xp[1], Nz=xp[2];
            float Ax=xp[3], Ay=xp[4], Az=xp[5];
            float Cx=xp[6], Cy=xp[7], Cz=xp[8];
            float v1x=Cx-Ax, v1y=Cy-Ay, v1z=Cz-Az;
            float v2x=Nx-Ax, v2y=Ny-Ay, v2z=Nz-Az;
            float n1 = sqrtf(v1x*v1x + v1y*v1y + v1z*v1z) + 1e-8f;
            e1x=v1x/n1; e1y=v1y/n1; e1z=v1z/n1;
            float dp = e1x*v2x + e1y*v2y + e1z*v2z;
            float u2x = v2x - dp*e1x, u2y = v2y - dp*e1y, u2z = v2z - dp*e1z;
            float n2 = sqrtf(u2x*u2x + u2y*u2y + u2z*u2z) + 1e-8f;
            e2x=u2x/n2; e2y=u2y/n2; e2z=u2z/n2;
            e3x = e1y*e2z - e1z*e2y;
            e3y = e1z*e2x - e1x*e2z;
            e3z = e1x*e2y - e1y*e2x;
            // row `row` of RTF0 = [e1[row], e2[row], e3[row], Ca[row]]
            float Tr = (row == 0) ? Ax : (row == 1) ? Ay : Az;
            v0[0] = (row == 0) ? e1x : (row == 1) ? e1y : e1z;
            v0[1] = (row == 0) ? e2x : (row == 1) ? e2y : e2z;
            v0[2] = (row == 0) ? e3x : (row == 1) ? e3y : e3z;
            v0[3] = Tr;
            M0t = Tr;
        }
    }
    __syncthreads();   // staging region free; sF now the frame buffer

    if (active) {
        float* wf = sF + r * FSTRIDE;
        const float* rtbase = RTs + (size_t)s * 112;

        // frame 0
        st4(wf + 0*16 + row*4, v0[0], v0[1], v0[2], v0[3]);

        // frames 1..3: v0 @ RTk @ rotX(ak)
#pragma unroll
        for (int k = 0; k < 3; ++k) {
            float Bm[16]; load16(Bm, rtbase + k*16);
            float w[4];
            vrow_mat(w, v0, Bm);
            vrotX(w, ca[k], sa[k]);
            st4(wf + (k+1)*16 + row*4, w[0], w[1], w[2], w[3]);
        }

        // frame 8: rows 0..2: v0[0:3] @ C1 @ C2, translation unchanged
        if (row < 3) {
            const float* bx = bxyz + (size_t)s * 108;
            float4 b0 = ((const float4*)bx)[0];
            float4 b1 = ((const float4*)bx)[1];
            float4 b2 = ((const float4*)bx)[2];
            float4 b4 = ((const float4*)bx)[4];
            float NCrx = 0.5f*(b2.x+b0.x), NCry = 0.5f*(b2.y+b0.y), NCrz = 0.5f*(b2.z+b0.z);
            float CBAx = b4.x-b1.x, CBAy = b4.y-b1.y, CBAz = b4.z-b1.z;
            float NCAx = NCrx-b1.x, NCAy = NCry-b1.y, NCAz = NCrz-b1.z;
            float a1x = CBAy*NCAz - CBAz*NCAy;
            float a1y = CBAz*NCAx - CBAx*NCAz;
            float a1z = CBAx*NCAy - CBAy*NCAx;
            float a1n = sqrtf(a1x*a1x + a1y*a1y + a1z*a1z) + 1e-8f;
            a1x/=a1n; a1y/=a1n; a1z/=a1n;
            float NCpx = b2.x-b0.x, NCpy = b2.y-b0.y, NCpz = b2.z-b0.z;
            float num = NCpx*NCrx + NCpy*NCry + NCpz*NCrz;
            float den = NCrx*NCrx + NCry*NCry + NCrz*NCrz;
            float tq  = num / den;
            float NCppx = NCpx - tq*NCrx, NCppy = NCpy - tq*NCry, NCppz = NCpz - tq*NCrz;
            float a2x = CBAy*NCppz - CBAz*NCppy;
            float a2y = CBAz*NCppx - CBAx*NCppz;
            float a2z = CBAx*NCppy - CBAy*NCppx;
            float a2n = sqrtf(a2x*a2x + a2y*a2y + a2z*a2z) + 1e-8f;
            a2x/=a2n; a2y/=a2n; a2z/=a2n;

            float C1[9], C2[9];
            rot_axis3(C1, ca[7], sa[7], a1x, a1y, a1z);
            rot_axis3(C2, ca[8], sa[8], a2x, a2y, a2z);
            float t0, t1, t2;
            t0 = v0[0]*C1[0]; t0 = fmaf(v0[1], C1[3], t0); t0 = fmaf(v0[2], C1[6], t0);
            t1 = v0[0]*C1[1]; t1 = fmaf(v0[1], C1[4], t1); t1 = fmaf(v0[2], C1[7], t1);
            t2 = v0[0]*C1[2]; t2 = fmaf(v0[1], C1[5], t2); t2 = fmaf(v0[2], C1[8], t2);
            float u0, u1, u2;
            u0 = t0*C2[0]; u0 = fmaf(t1, C2[3], u0); u0 = fmaf(t2, C2[6], u0);
            u1 = t0*C2[1]; u1 = fmaf(t1, C2[4], u1); u1 = fmaf(t2, C2[7], u1);
            u2 = t0*C2[2]; u2 = fmaf(t1, C2[5], u2); u2 = fmaf(t2, C2[8], u2);
            v8[0]=u0; v8[1]=u1; v8[2]=u2; v8[3]=M0t;
        }
        st4(wf + 8*16 + row*4, v8[0], v8[1], v8[2], v8[3]);

        // frame 4: v8 @ RT3 @ rotX(a3) @ rotZ(a9)
        float p[4];
        {
            float Bm[16]; load16(Bm, rtbase + 3*16);
            vrow_mat(p, v8, Bm);
            vrotX(p, ca[3], sa[3]);
            vrotZ(p, ca[9], sa[9]);
            st4(wf + 4*16 + row*4, p[0], p[1], p[2], p[3]);
        }

        // frames 5..7: serial chain
#pragma unroll
        for (int k = 4; k < 7; ++k) {
            float Bm[16]; load16(Bm, rtbase + k*16);
            float q[4];
            vrow_mat(q, p, Bm);
            vrotX(q, ca[k], sa[k]);
            st4(wf + (k+1)*16 + row*4, q[0], q[1], q[2], q[3]);
            p[0]=q[0]; p[1]=q[1]; p[2]=q[2]; p[3]=q[3];
        }
    }
    __syncthreads();

    // ---- coalesced LDS -> outF copy (global layout stride 144, LDS 148) ----
    {
        const int n4 = nres * 36;   // float4 count
        float4* dst = reinterpret_cast<float4*>(outF + (size_t)resBase * 144);
        for (int j = tid; j < n4; j += TPB) {
            unsigned uj = (unsigned)j;
            unsigned rr = uj / 36u;
            unsigned o  = uj - rr * 36u;
            dst[j] = *reinterpret_cast<const float4*>(sF + rr * FSTRIDE + o * 4);
        }
    }

    // ---- atom phase: one element per thread-iteration, coalesced outX ----
    {
        const int total = nres * 81;
        float* ox = outX + (size_t)resBase * 81;
        for (int i = tid; i < total; i += TPB) {
            unsigned ui = (unsigned)i;
            unsigned r2 = ui / 81u;
            unsigned c  = ui - r2 * 81u;
            unsigned a  = c / 3u;
            unsigned d  = c - a * 3u;
            int s2  = sSeq[r2];
            int ii  = s2 * 27 + (int)a;
            int idx = bidx[ii];
            float4 bv = reinterpret_cast<const float4*>(bxyz)[ii];
            float4 fr = *reinterpret_cast<const float4*>(sF + r2*FSTRIDE + idx*16 + d*4);
            float val = fr.x * bv.x;
            val = fmaf(fr.y, bv.y, val);
            val = fmaf(fr.z, bv.z, val);
            val = fmaf(fr.w, bv.w, val);
            ox[i] = val;
        }
    }
}

extern "C" void kernel_launch(void* const* d_in, const int* in_sizes, int n_in,
                              void* d_out, int out_size, void* d_ws, size_t ws_size,
                              hipStream_t stream) {
    const float* xyz    = (const float*)d_in[0];
    const float* alphas = (const float*)d_in[1];
    const float* RTs    = (const float*)d_in[2];
    const float* bxyz   = (const float*)d_in[3];
    const int*   seq    = (const int*)d_in[4];
    const int*   bidx   = (const int*)d_in[5];
    const int L = in_sizes[4];
    float* outF = (float*)d_out;
    float* outX = outF + (size_t)L * 144;

    const int grid = (L + RPB - 1) / RPB;
    hipLaunchKernelGGL(caac_kernel, dim3(grid), dim3(TPB), 0, stream,
                       xyz, alphas, RTs, bxyz, seq, bidx, outF, outX, L);
}